// Round 3
// baseline (727.824 us; speedup 1.0000x reference)
//
#include <hip/hip_runtime.h>
#include <hip/hip_bf16.h>

#define T_TOKENS 4096
#define DM 1024
#define DF 4096
#define NE 8
#define MAXROWS 9216   // 8192 + 8*128 padding
#define KSPLIT 4       // gemm2 split-K factor

typedef float f32x4 __attribute__((ext_vector_type(4)));
typedef short bf16x8 __attribute__((ext_vector_type(8)));

__device__ __forceinline__ unsigned short f2bf(float f) {
    union { float f; unsigned int u; } v; v.f = f;
    unsigned int r = v.u + 0x7fffu + ((v.u >> 16) & 1u);
    return (unsigned short)(r >> 16);
}

// async global->LDS, 16B per lane; LDS dest = wave-uniform base + lane*16
__device__ __forceinline__ void g2l16(const void* g, void* l) {
    __builtin_amdgcn_global_load_lds(
        (const __attribute__((address_space(1))) void*)g,
        (__attribute__((address_space(3))) void*)l, 16, 0, 0);
}

// ---------------- gating: logits -> top2 (softmax monotone, skip it) ----------------
__global__ __launch_bounds__(256) void gate_kernel(
    const float* __restrict__ x, const float* __restrict__ Wg, const float* __restrict__ bg,
    int* __restrict__ counts, int* __restrict__ topk)
{
    int wave = threadIdx.x >> 6;
    int lane = threadIdx.x & 63;
    int t = blockIdx.x * 4 + wave;
    float acc[NE];
#pragma unroll
    for (int e = 0; e < NE; e++) acc[e] = 0.f;
    const float* xr = x + (size_t)t * DM;
#pragma unroll
    for (int i = 0; i < DM / 64; i++) {
        int d = lane + i * 64;
        float xv = xr[d];
        const float4* wg = (const float4*)(Wg + d * NE);
        float4 w0 = wg[0], w1 = wg[1];
        acc[0] += xv * w0.x; acc[1] += xv * w0.y; acc[2] += xv * w0.z; acc[3] += xv * w0.w;
        acc[4] += xv * w1.x; acc[5] += xv * w1.y; acc[6] += xv * w1.z; acc[7] += xv * w1.w;
    }
#pragma unroll
    for (int e = 0; e < NE; e++) {
#pragma unroll
        for (int off = 32; off > 0; off >>= 1)
            acc[e] += __shfl_down(acc[e], off);
    }
    if (lane == 0) {
        float lg[NE];
#pragma unroll
        for (int e = 0; e < NE; e++) lg[e] = acc[e] + bg[e];
        int b1i = 0; float b1v = lg[0];
        for (int e = 1; e < NE; e++) if (lg[e] > b1v) { b1v = lg[e]; b1i = e; }
        int b2i = -1; float b2v = -1e30f;
        for (int e = 0; e < NE; e++) {
            if (e == b1i) continue;
            if (b2i < 0 || lg[e] > b2v) { b2v = lg[e]; b2i = e; }
        }
        topk[t * 2 + 0] = b1i;
        topk[t * 2 + 1] = b2i;
        atomicAdd(&counts[b1i], 1);
        atomicAdd(&counts[b2i], 1);
    }
}

// ---------------- offsets (128-padded) + cursor init + list=-1 fill ----------------
__global__ __launch_bounds__(256) void prep_kernel(
    const int* __restrict__ counts, int* __restrict__ offsets,
    int* __restrict__ cur, int* __restrict__ list)
{
    if (threadIdx.x == 0) {
        int s = 0;
        for (int e = 0; e < NE; e++) {
            offsets[e] = s; cur[e] = s;
            s += (counts[e] + 127) & ~127;
        }
        offsets[NE] = s;
    }
    for (int i = threadIdx.x; i < MAXROWS; i += 256) list[i] = -1;
}

// ---------------- parallel scatter: per-block LDS hist -> range claim -> write -----
__global__ __launch_bounds__(256) void scatter_kernel(
    const int* __restrict__ topk, int* __restrict__ cur, int* __restrict__ list)
{
    __shared__ int hist[NE], base[NE], lofs[NE];
    const int t = threadIdx.x;
    const int i0 = blockIdx.x * 512;
    if (t < NE) { hist[t] = 0; lofs[t] = 0; }
    __syncthreads();
    int ea = topk[i0 + 2 * t], eb = topk[i0 + 2 * t + 1];
    atomicAdd(&hist[ea], 1);
    atomicAdd(&hist[eb], 1);
    __syncthreads();
    if (t < NE) base[t] = atomicAdd(&cur[t], hist[t]);
    __syncthreads();
    int pa = base[ea] + atomicAdd(&lofs[ea], 1);
    list[pa] = (i0 + 2 * t) >> 1;
    int pb = base[eb] + atomicAdd(&lofs[eb], 1);
    list[pb] = (i0 + 2 * t + 1) >> 1;
}

// ---------------- x fp32 -> bf16 ----------------
__global__ __launch_bounds__(256) void cvt_x_kernel(
    const float* __restrict__ x, unsigned short* __restrict__ xb)
{
    int i = (blockIdx.x * 256 + threadIdx.x) * 4;
    float4 v = *(const float4*)(x + i);
    unsigned short o[4] = { f2bf(v.x), f2bf(v.y), f2bf(v.z), f2bf(v.w) };
    *(uint2*)(xb + i) = *(const uint2*)o;
}

// ---------------- W [e][K][N] fp32 -> [e][N][K] bf16 (tile transpose via LDS) ------
__global__ __launch_bounds__(256) void tr_cvt_kernel(
    const float* __restrict__ src, unsigned short* __restrict__ dst, int K, int N)
{
    const int e = blockIdx.z;
    src += (size_t)e * K * N;
    dst += (size_t)e * N * K;
    const int n0 = blockIdx.x * 64, k0 = blockIdx.y * 64;
    __shared__ unsigned short tile[64][72];
    const int t = threadIdx.x;
    const int nx = (t & 15) * 4;   // 4 consecutive n (float4 load)
    const int ky = t >> 4;         // 16 k rows per pass
#pragma unroll
    for (int r = 0; r < 4; r++) {
        int k = ky + r * 16;
        float4 v = *(const float4*)(src + (size_t)(k0 + k) * N + n0 + nx);
        tile[nx + 0][k] = f2bf(v.x);
        tile[nx + 1][k] = f2bf(v.y);
        tile[nx + 2][k] = f2bf(v.z);
        tile[nx + 3][k] = f2bf(v.w);
    }
    __syncthreads();
    const int kx = (t & 7) * 8;    // 8 consecutive k (16B store)
    const int ny = t >> 3;         // 32 n rows per pass
#pragma unroll
    for (int r = 0; r < 2; r++) {
        int n = ny + r * 32;
        *(uint4*)(dst + (size_t)(n0 + n) * K + k0 + kx) = *(const uint4*)&tile[n][kx];
    }
}

// ---------------- GEMM1: H = relu(gather(xb) @ W1T^T + b1), all experts fused ------
__global__ __launch_bounds__(256) void gemm1_kernel(
    const unsigned short* __restrict__ xb, const unsigned short* __restrict__ W1T,
    const float* __restrict__ b1, const int* __restrict__ offsets,
    const int* __restrict__ list, unsigned short* __restrict__ H)
{
    const int total = offsets[NE];
    const int row0 = blockIdx.x * 128;
    if (row0 >= total) return;
    int e = 0;
    while (row0 >= offsets[e + 1]) e++;
    const int n0 = blockIdx.y * 128;

    __shared__ unsigned short Asm[128 * 32];
    __shared__ unsigned short Bsm[128 * 32];

    const int tid = threadIdx.x;
    const int w = tid >> 6, lane = tid & 63;
    const int quad = lane >> 4, l16 = lane & 15;
    const int wm = w >> 1, wn = w & 1;

    const int sr = lane >> 2;        // row within 16-row chunk
    const int sc = (lane & 3) * 8;   // k offset (8 bf16 = 16B)
    const int ra1 = 32 * w + sr, ra2 = ra1 + 16;
    int t1 = list[row0 + ra1]; if (t1 < 0) t1 = 0;
    int t2 = list[row0 + ra2]; if (t2 < 0) t2 = 0;
    const unsigned short* gA1 = xb + (size_t)t1 * DM + sc;
    const unsigned short* gA2 = xb + (size_t)t2 * DM + sc;
    const unsigned short* Wb = W1T + (size_t)e * DF * DM;
    const unsigned short* gB1 = Wb + (size_t)(n0 + 32 * w + sr) * DM + sc;
    const unsigned short* gB2 = gB1 + (size_t)16 * DM;
    unsigned short* lA1 = Asm + (2 * w) * 512;
    unsigned short* lA2 = Asm + (2 * w + 1) * 512;
    unsigned short* lB1 = Bsm + (2 * w) * 512;
    unsigned short* lB2 = Bsm + (2 * w + 1) * 512;

    f32x4 acc[4][4];
#pragma unroll
    for (int i = 0; i < 4; i++)
#pragma unroll
        for (int j = 0; j < 4; j++) acc[i][j] = (f32x4){0.f, 0.f, 0.f, 0.f};

    for (int kk = 0; kk < DM; kk += 32) {
        g2l16(gA1 + kk, lA1);
        g2l16(gA2 + kk, lA2);
        g2l16(gB1 + kk, lB1);
        g2l16(gB2 + kk, lB2);
        __syncthreads();
        bf16x8 af[4];
#pragma unroll
        for (int i = 0; i < 4; i++)
            af[i] = *(const bf16x8*)&Asm[(wm * 64 + i * 16 + l16) * 32 + quad * 8];
#pragma unroll
        for (int j = 0; j < 4; j++) {
            bf16x8 bf = *(const bf16x8*)&Bsm[(wn * 64 + j * 16 + l16) * 32 + quad * 8];
#pragma unroll
            for (int i = 0; i < 4; i++)
                acc[i][j] = __builtin_amdgcn_mfma_f32_16x16x32_bf16(af[i], bf, acc[i][j], 0, 0, 0);
        }
        __syncthreads();
    }

    const float* bias = b1 + e * DF;
#pragma unroll
    for (int j = 0; j < 4; j++) {
        int n = n0 + wn * 64 + j * 16 + l16;
        float bj = bias[n];
#pragma unroll
        for (int i = 0; i < 4; i++) {
            int row = row0 + wm * 64 + i * 16 + quad * 4;
#pragma unroll
            for (int r = 0; r < 4; r++) {
                float v = acc[i][j][r] + bj;
                v = fmaxf(v, 0.f);
                H[(size_t)(row + r) * DF + n] = f2bf(v);
            }
        }
    }
}

// ---------------- GEMM2: out[tok] += H @ W2T^T + b2, fused + split-K ---------------
__global__ __launch_bounds__(256) void gemm2_kernel(
    const unsigned short* __restrict__ H, const unsigned short* __restrict__ W2T,
    const float* __restrict__ b2, const int* __restrict__ offsets,
    const int* __restrict__ list, float* __restrict__ out)
{
    const int total = offsets[NE];
    const int row0 = blockIdx.y * 128;
    if (row0 >= total) return;
    int e = 0;
    while (row0 >= offsets[e + 1]) e++;
    const int n0 = (blockIdx.x & 7) * 128;       // n fastest: adjacent blocks share A slice
    const int kc = blockIdx.x >> 3;
    const int k0 = kc * (DF / KSPLIT);

    __shared__ unsigned short Asm[128 * 32];
    __shared__ unsigned short Bsm[128 * 32];

    const int tid = threadIdx.x;
    const int w = tid >> 6, lane = tid & 63;
    const int quad = lane >> 4, l16 = lane & 15;
    const int wm = w >> 1, wn = w & 1;

    const int sr = lane >> 2;
    const int sc = (lane & 3) * 8;
    const unsigned short* gA1 = H + (size_t)(row0 + 32 * w + sr) * DF + sc;
    const unsigned short* gA2 = gA1 + (size_t)16 * DF;
    const unsigned short* Wb = W2T + (size_t)e * DM * DF;
    const unsigned short* gB1 = Wb + (size_t)(n0 + 32 * w + sr) * DF + sc;
    const unsigned short* gB2 = gB1 + (size_t)16 * DF;
    unsigned short* lA1 = Asm + (2 * w) * 512;
    unsigned short* lA2 = Asm + (2 * w + 1) * 512;
    unsigned short* lB1 = Bsm + (2 * w) * 512;
    unsigned short* lB2 = Bsm + (2 * w + 1) * 512;

    f32x4 acc[4][4];
#pragma unroll
    for (int i = 0; i < 4; i++)
#pragma unroll
        for (int j = 0; j < 4; j++) acc[i][j] = (f32x4){0.f, 0.f, 0.f, 0.f};

    for (int kk = k0; kk < k0 + DF / KSPLIT; kk += 32) {
        g2l16(gA1 + kk, lA1);
        g2l16(gA2 + kk, lA2);
        g2l16(gB1 + kk, lB1);
        g2l16(gB2 + kk, lB2);
        __syncthreads();
        bf16x8 af[4];
#pragma unroll
        for (int i = 0; i < 4; i++)
            af[i] = *(const bf16x8*)&Asm[(wm * 64 + i * 16 + l16) * 32 + quad * 8];
#pragma unroll
        for (int j = 0; j < 4; j++) {
            bf16x8 bf = *(const bf16x8*)&Bsm[(wn * 64 + j * 16 + l16) * 32 + quad * 8];
#pragma unroll
            for (int i = 0; i < 4; i++)
                acc[i][j] = __builtin_amdgcn_mfma_f32_16x16x32_bf16(af[i], bf, acc[i][j], 0, 0, 0);
        }
        __syncthreads();
    }

    const float* bias = b2 + e * DM;
#pragma unroll
    for (int j = 0; j < 4; j++) {
        int n = n0 + wn * 64 + j * 16 + l16;
        float bj = (kc == 0) ? bias[n] : 0.f;
#pragma unroll
        for (int i = 0; i < 4; i++) {
            int row = row0 + wm * 64 + i * 16 + quad * 4;
#pragma unroll
            for (int r = 0; r < 4; r++) {
                int tk = list[row + r];
                if (tk >= 0)
                    atomicAdd(&out[(size_t)tk * DM + n], acc[i][j][r] + bj);
            }
        }
    }
}

extern "C" void kernel_launch(void* const* d_in, const int* in_sizes, int n_in,
                              void* d_out, int out_size, void* d_ws, size_t ws_size,
                              hipStream_t stream)
{
    const float* x  = (const float*)d_in[0];
    const float* Wg = (const float*)d_in[1];
    const float* bg = (const float*)d_in[2];
    const float* W1 = (const float*)d_in[3];
    const float* b1 = (const float*)d_in[4];
    const float* W2 = (const float*)d_in[5];
    const float* b2 = (const float*)d_in[6];
    float* out = (float*)d_out;

    char* ws = (char*)d_ws;
    int* counts  = (int*)(ws + 0);            // 8 ints
    int* offsets = (int*)(ws + 64);           // 9 ints
    int* cur     = (int*)(ws + 128);          // 8 ints
    int* topk    = (int*)(ws + 256);          // 8192 ints
    int* list    = (int*)(ws + 33024);        // 9216 ints
    unsigned short* xb = (unsigned short*)(ws + (1u << 20));           // 8 MB slot
    unsigned short* WT = (unsigned short*)(ws + (16u << 20));          // 64 MB (W1T then W2T)
    unsigned short* Hb = (unsigned short*)(ws + (80u << 20));          // 75.5 MB

    hipMemsetAsync(counts, 0, NE * sizeof(int), stream);
    hipMemsetAsync(d_out, 0, (size_t)out_size * sizeof(float), stream);

    gate_kernel<<<T_TOKENS / 4, 256, 0, stream>>>(x, Wg, bg, counts, topk);
    prep_kernel<<<1, 256, 0, stream>>>(counts, offsets, cur, list);
    scatter_kernel<<<T_TOKENS * 2 / 512, 256, 0, stream>>>(topk, cur, list);
    cvt_x_kernel<<<T_TOKENS * DM / 1024, 256, 0, stream>>>(x, xb);

    // W1: [e][K=DM][N=DF] -> [e][DF][DM]
    tr_cvt_kernel<<<dim3(DF / 64, DM / 64, NE), 256, 0, stream>>>(W1, WT, DM, DF);
    gemm1_kernel<<<dim3(MAXROWS / 128, DF / 128), 256, 0, stream>>>(
        xb, WT, b1, offsets, list, Hb);

    // W2: [e][K=DF][N=DM] -> [e][DM][DF]  (reuses WT buffer; stream serializes)
    tr_cvt_kernel<<<dim3(DM / 64, DF / 64, NE), 256, 0, stream>>>(W2, WT, DF, DM);
    gemm2_kernel<<<dim3(8 * KSPLIT, MAXROWS / 128), 256, 0, stream>>>(
        Hb, WT, b2, offsets, list, out);
}